// Round 1
// 37148.001 us; speedup vs baseline: 1.1826x; 1.1826x over previous
//
#include <hip/hip_runtime.h>
#include <math.h>

#define Bb 32
#define Lmax 400
#define Tt 64
#define Ee 256
#define Hh 512
#define H2 1024
#define Vv 32000
#define OOV 100
#define VX (Vv+OOV)
#define PAD_ID 0
#define UNK_ID 1
#define START_ID 2

__device__ __forceinline__ float sigf(float x){ return 1.0f/(1.0f+expf(-x)); }
__device__ __forceinline__ float bf2f(unsigned int u){ u <<= 16; return __uint_as_float(u); }

// ================= encoder weight packing =================
// wip[(dir*256+k)*512+n] = float4{Wi[k][g*512+n], g=0..3}; whp analog (K=512); bp[dir*512+n]=bias gates
__global__ __launch_bounds__(256) void pack_enc_k(
    const float* __restrict__ Wi_f, const float* __restrict__ Wh_f, const float* __restrict__ b_f,
    const float* __restrict__ Wi_b, const float* __restrict__ Wh_b, const float* __restrict__ b_b,
    float4* __restrict__ wip, float4* __restrict__ whp, float4* __restrict__ bp)
{
  int o = blockIdx.x*256 + threadIdx.x;
  if (o < 2*256*512) {
    int n = o & 511; int k = (o >> 9) & 255; int dir = o >> 17;
    const float* W = dir ? Wi_b : Wi_f;
    wip[o] = make_float4(W[k*2048+n], W[k*2048+512+n], W[k*2048+1024+n], W[k*2048+1536+n]);
  }
  if (o < 2*512*512) {
    int n = o & 511; int k = (o >> 9) & 511; int dir = o >> 18;
    const float* W = dir ? Wh_b : Wh_f;
    whp[o] = make_float4(W[k*2048+n], W[k*2048+512+n], W[k*2048+1024+n], W[k*2048+1536+n]);
  }
  if (o < 2*512) {
    int n = o & 511; int dir = o >> 9;
    const float* bs = dir ? b_b : b_f;
    bp[o] = make_float4(bs[n], bs[512+n], bs[1024+n], bs[1536+n]);
  }
}

// ================= encoder step: K-split-4, LDS-staged weights, float4 h/x loads =================
// grid 256 = dir(2) x ngroup(128, 4 n each); block 512 = b(32) x nl(4) x ks(4)
__global__ __launch_bounds__(512) void enc_step2_k(
    const float4* __restrict__ wip, const float4* __restrict__ whp, const float4* __restrict__ bp,
    const float* __restrict__ emb, const int* __restrict__ x,
    float* __restrict__ c_buf, float* __restrict__ enc_out, int t)
{
  __shared__ float4 wi_s[256*4];
  __shared__ float4 wh_s[512*4];
  __shared__ float4 red_s[4*128];
  int bx = blockIdx.x;
  int dir = bx >> 7, ng = bx & 127;
  int tid = threadIdx.x;
  int b = tid & 31, nl = (tid >> 5) & 3, ks = tid >> 7;
  int n = ng*4 + nl;
  for (int i = tid; i < 1024; i += 512) {
    int k = i >> 2, l = i & 3;
    wi_s[i] = wip[(dir*256 + k)*512 + ng*4 + l];
  }
  for (int i = tid; i < 2048; i += 512) {
    int k = i >> 2, l = i & 3;
    wh_s[i] = whp[(dir*512 + k)*512 + ng*4 + l];
  }
  __syncthreads();
  int tt = dir ? (Lmax-1-t) : t;
  int tok = x[b*Lmax + tt];
  const float* xr = emb + (size_t)tok*Ee;
  float4 acc = make_float4(0.f,0.f,0.f,0.f);
  if (t > 0) {
    int pt = dir ? (tt+1) : (tt-1);
    const float4* hb4 = (const float4*)(enc_out + ((size_t)b*Lmax + pt)*H2 + dir*Hh);
    #pragma unroll 4
    for (int k4 = ks*32; k4 < ks*32+32; ++k4) {
      float4 hv = hb4[k4];
      float4 w0 = wh_s[(k4*4+0)*4 + nl];
      float4 w1 = wh_s[(k4*4+1)*4 + nl];
      float4 w2 = wh_s[(k4*4+2)*4 + nl];
      float4 w3 = wh_s[(k4*4+3)*4 + nl];
      acc.x = fmaf(hv.x,w0.x,acc.x); acc.y = fmaf(hv.x,w0.y,acc.y);
      acc.z = fmaf(hv.x,w0.z,acc.z); acc.w = fmaf(hv.x,w0.w,acc.w);
      acc.x = fmaf(hv.y,w1.x,acc.x); acc.y = fmaf(hv.y,w1.y,acc.y);
      acc.z = fmaf(hv.y,w1.z,acc.z); acc.w = fmaf(hv.y,w1.w,acc.w);
      acc.x = fmaf(hv.z,w2.x,acc.x); acc.y = fmaf(hv.z,w2.y,acc.y);
      acc.z = fmaf(hv.z,w2.z,acc.z); acc.w = fmaf(hv.z,w2.w,acc.w);
      acc.x = fmaf(hv.w,w3.x,acc.x); acc.y = fmaf(hv.w,w3.y,acc.y);
      acc.z = fmaf(hv.w,w3.z,acc.z); acc.w = fmaf(hv.w,w3.w,acc.w);
    }
  }
  const float4* xr4 = (const float4*)xr;
  #pragma unroll 4
  for (int k4 = ks*16; k4 < ks*16+16; ++k4) {
    float4 xv = xr4[k4];
    float4 w0 = wi_s[(k4*4+0)*4 + nl];
    float4 w1 = wi_s[(k4*4+1)*4 + nl];
    float4 w2 = wi_s[(k4*4+2)*4 + nl];
    float4 w3 = wi_s[(k4*4+3)*4 + nl];
    acc.x = fmaf(xv.x,w0.x,acc.x); acc.y = fmaf(xv.x,w0.y,acc.y);
    acc.z = fmaf(xv.x,w0.z,acc.z); acc.w = fmaf(xv.x,w0.w,acc.w);
    acc.x = fmaf(xv.y,w1.x,acc.x); acc.y = fmaf(xv.y,w1.y,acc.y);
    acc.z = fmaf(xv.y,w1.z,acc.z); acc.w = fmaf(xv.y,w1.w,acc.w);
    acc.x = fmaf(xv.z,w2.x,acc.x); acc.y = fmaf(xv.z,w2.y,acc.y);
    acc.z = fmaf(xv.z,w2.z,acc.z); acc.w = fmaf(xv.z,w2.w,acc.w);
    acc.x = fmaf(xv.w,w3.x,acc.x); acc.y = fmaf(xv.w,w3.y,acc.y);
    acc.z = fmaf(xv.w,w3.z,acc.z); acc.w = fmaf(xv.w,w3.w,acc.w);
  }
  red_s[ks*128 + (tid & 127)] = acc;
  __syncthreads();
  if (tid < 128) {
    float4 a0 = red_s[tid], a1 = red_s[128+tid], a2 = red_s[256+tid], a3 = red_s[384+tid];
    float4 bb = bp[dir*512 + n];
    float zi = a0.x+a1.x+a2.x+a3.x + bb.x;
    float zf = a0.y+a1.y+a2.y+a3.y + bb.y;
    float zg = a0.z+a1.z+a2.z+a3.z + bb.z;
    float zo = a0.w+a1.w+a2.w+a3.w + bb.w;
    int ci = (dir*32 + b)*Hh + n;
    float cv = (t==0) ? 0.f : c_buf[ci];
    float cn = sigf(zf)*cv + sigf(zi)*tanhf(zg);
    float hn = sigf(zo)*tanhf(cn);
    c_buf[ci] = cn;
    enc_out[((size_t)b*Lmax + tt)*H2 + dir*Hh + n] = hn;
  }
}

// ================= decoder init =================
__global__ __launch_bounds__(256) void init_dec_k(
    const float* __restrict__ enc_out, float* __restrict__ cat_buf, int* __restrict__ dec_in)
{
  int idx = blockIdx.x*256 + threadIdx.x;
  if (idx < Bb*H2) {
    int b = idx >> 10, n = idx & 1023;
    float v = (n < Hh) ? enc_out[((size_t)b*Lmax + (Lmax-1))*H2 + n]
                       : enc_out[(size_t)b*Lmax*H2 + n];
    cat_buf[b*3*H2 + n] = v;
  }
  if (idx < Bb) dec_in[idx] = START_ID;
}

// ================= GRU matmuls: K-split x2 for occupancy (768 blocks = 12 waves/CU) =================
// grid 768 = ng(48 x 64n) x bg(8 x 4b) x kq(2); block 256 = nl(64) x bl(4)
__global__ __launch_bounds__(256) void gru_mm_k(
    const float* __restrict__ emb, const int* __restrict__ dec_in,
    const float* __restrict__ cat_buf, const float* __restrict__ Wi,
    const float* __restrict__ Wh, const float* __restrict__ bias,
    float* __restrict__ zi_buf, float* __restrict__ zh_buf)
{
  int bx = blockIdx.x;
  int ng = bx % 48; int bg = (bx / 48) & 7; int kq = bx / 384;
  int nl = threadIdx.x & 63, bl = threadIdx.x >> 6;
  int n = ng*64 + nl, b = bg*4 + bl;
  const float* hr = cat_buf + b*3*H2;
  float zh = 0.f;
  int k0 = kq*512;
  #pragma unroll 4
  for (int k = k0; k < k0+512; ++k)
    zh = fmaf(hr[k], Wh[(size_t)k*3*H2 + n], zh);
  zh_buf[(size_t)(kq*Bb + b)*3*H2 + n] = zh;
  if (kq == 0) {
    const float* er = emb + (size_t)dec_in[b]*Ee;
    float zi = bias[n];
    #pragma unroll 4
    for (int k = 0; k < Ee; ++k)
      zi = fmaf(er[k], Wi[(size_t)k*3*H2 + n], zi);
    zi_buf[b*3*H2 + n] = zi;
  }
}

__global__ __launch_bounds__(256) void gru_comb_k(
    const float* __restrict__ zi_buf, const float* __restrict__ zh_buf,
    float* __restrict__ cat_buf, float* __restrict__ prebuf, int t)
{
  int idx = blockIdx.x*256 + threadIdx.x;   // 32768
  int b = idx >> 10, n = idx & 1023;
  const float* zi  = zi_buf + b*3*H2;
  const float* zh0 = zh_buf + (size_t)b*3*H2;
  const float* zh1 = zh_buf + (size_t)(Bb + b)*3*H2;
  float zhr = zh0[n]      + zh1[n];
  float zhz = zh0[H2+n]   + zh1[H2+n];
  float zhg = zh0[2*H2+n] + zh1[2*H2+n];
  float r  = sigf(zi[n] + zhr);
  float z  = sigf(zi[H2+n] + zhz);
  float nn = tanhf(zi[2*H2+n] + r*zhg);
  float hold = cat_buf[b*3*H2 + n];
  float h = (1.0f - z)*nn + z*hold;
  cat_buf[b*3*H2 + n] = h;
  prebuf[((size_t)b*Tt + t)*H2 + n] = h;
}

// ================= attention queries: K-split x4 (512 blocks = 8 waves/CU) =================
// grid 512 = ng(16 x 64n) x bg(8 x 4b) x kq(4); partials summed in att_sc_k
__global__ __launch_bounds__(256) void qq_k(
    const float* __restrict__ cat_buf, const float* __restrict__ Wea,
    const float* __restrict__ Wda, float* __restrict__ qp, float* __restrict__ qdp)
{
  int bx = blockIdx.x;
  int ng = bx & 15, bg = (bx >> 4) & 7, kq = bx >> 7;
  int nl = threadIdx.x & 63, bl = threadIdx.x >> 6;
  int n = ng*64 + nl, b = bg*4 + bl;
  const float* hr = cat_buf + b*3*H2 + kq*256;
  const float* wa = Wea + (size_t)(kq*256)*H2 + n;
  const float* wd = Wda + (size_t)(kq*256)*H2 + n;
  float s1 = 0.f, s2 = 0.f;
  #pragma unroll 4
  for (int k = 0; k < 256; ++k) {
    float hv = hr[k];
    s1 = fmaf(hv, wa[(size_t)k*H2], s1);
    s2 = fmaf(hv, wd[(size_t)k*H2], s2);
  }
  qp [(size_t)(kq*Bb + b)*H2 + n] = s1;
  qdp[(size_t)(kq*Bb + b)*H2 + n] = s2;
}

// ================= attention scores (float4, sums 4 q-partials) =================
__global__ __launch_bounds__(256) void att_sc_k(
    const float* __restrict__ qp, const float* __restrict__ qdp,
    const float* __restrict__ enc_out, const float* __restrict__ prebuf,
    float* __restrict__ esc, float* __restrict__ ed, int t)
{
  int w = blockIdx.x*4 + (threadIdx.x >> 6);
  int lane = threadIdx.x & 63;
  int b = w / 464;
  int row = w - b*464;
  if (b >= Bb) return;
  float s = 0.0f;
  if (row < Lmax) {
    const float4* q0 = (const float4*)(qp + (size_t)(0*Bb + b)*H2);
    const float4* q1 = (const float4*)(qp + (size_t)(1*Bb + b)*H2);
    const float4* q2 = (const float4*)(qp + (size_t)(2*Bb + b)*H2);
    const float4* q3 = (const float4*)(qp + (size_t)(3*Bb + b)*H2);
    const float4* er = (const float4*)(enc_out + ((size_t)b*Lmax + row)*H2);
    #pragma unroll
    for (int j = 0; j < 4; ++j) {
      int idx = lane + 64*j;
      float4 a0 = q0[idx], a1 = q1[idx], a2 = q2[idx], a3 = q3[idx], e = er[idx];
      float ax = a0.x+a1.x+a2.x+a3.x;
      float ay = a0.y+a1.y+a2.y+a3.y;
      float az = a0.z+a1.z+a2.z+a3.z;
      float aw = a0.w+a1.w+a2.w+a3.w;
      s += ax*e.x + ay*e.y + az*e.z + aw*e.w;
    }
  } else {
    int tp = row - Lmax;
    if (tp >= t) { if (lane==0) ed[b*Tt+tp] = 0.0f; return; }
    const float4* q0 = (const float4*)(qdp + (size_t)(0*Bb + b)*H2);
    const float4* q1 = (const float4*)(qdp + (size_t)(1*Bb + b)*H2);
    const float4* q2 = (const float4*)(qdp + (size_t)(2*Bb + b)*H2);
    const float4* q3 = (const float4*)(qdp + (size_t)(3*Bb + b)*H2);
    const float4* pr = (const float4*)(prebuf + ((size_t)b*Tt + tp)*H2);
    #pragma unroll
    for (int j = 0; j < 4; ++j) {
      int idx = lane + 64*j;
      float4 a0 = q0[idx], a1 = q1[idx], a2 = q2[idx], a3 = q3[idx], e = pr[idx];
      float ax = a0.x+a1.x+a2.x+a3.x;
      float ay = a0.y+a1.y+a2.y+a3.y;
      float az = a0.z+a1.z+a2.z+a3.z;
      float aw = a0.w+a1.w+a2.w+a3.w;
      s += ax*e.x + ay*e.y + az*e.z + aw*e.w;
    }
  }
  for (int o = 32; o > 0; o >>= 1) s += __shfl_xor(s, o);
  if (lane == 0) { if (row < Lmax) esc[b*Lmax+row] = s; else ed[b*Tt + (row-Lmax)] = s; }
}

// ================= fused temporal-normalize + intra-dec softmax + contexts =================
// grid 512 = b(32) x kq(16 x 64k); block 256 = klane(64) x lstrip(4)
// Each block redundantly normalizes its b's attention row in LDS (reads accum ping-pong buf);
// block kq==0 writes enc_att (for final_k) and the new accum buffer.
__global__ __launch_bounds__(256) void ctx_norm_k(
    const float* __restrict__ esc, const float* __restrict__ acc_r, float* __restrict__ acc_w,
    float* __restrict__ enc_att, const float* __restrict__ ed,
    const float* __restrict__ enc_out, const float* __restrict__ prebuf,
    float* __restrict__ cat_buf, int t)
{
  __shared__ float att_s[Lmax];
  __shared__ float datt_s[Tt];
  __shared__ float red[256];
  int b = blockIdx.x >> 4, kq = blockIdx.x & 15;
  int tid = threadIdx.x;
  // phase 1: temporal normalization (exp / running-sum, then row-normalize)
  float loc = 0.f;
  for (int l = tid; l < Lmax; l += 256) {
    float ee = expf(esc[b*Lmax + l]);
    float a  = (t == 0) ? 0.f : acc_r[b*Lmax + l];
    float un = (t == 0) ? ee : ee / (a + 1e-10f);
    att_s[l] = un;
    loc += un;
    if (kq == 0) acc_w[b*Lmax + l] = a + ee;
  }
  red[tid] = loc; __syncthreads();
  for (int s = 128; s > 0; s >>= 1) { if (tid < s) red[tid] += red[tid+s]; __syncthreads(); }
  float inv = 1.0f / red[0];
  for (int l = tid; l < Lmax; l += 256) {
    float v = att_s[l] * inv;
    att_s[l] = v;
    if (kq == 0) enc_att[b*Lmax + l] = v;
  }
  // intra-decoder softmax (wave 0)
  if (tid < 64 && t > 0) {
    float v = (tid < t) ? ed[b*Tt + tid] : -INFINITY;
    float m = v;
    for (int o = 32; o > 0; o >>= 1) m = fmaxf(m, __shfl_xor(m, o));
    float p = (tid < t) ? expf(v - m) : 0.f;
    float ss = p;
    for (int o = 32; o > 0; o >>= 1) ss += __shfl_xor(ss, o);
    datt_s[tid] = p / ss;
  }
  __syncthreads();
  // phase 2: contexts for this block's 64 k, 4 l-strips each, deterministic LDS reduce
  int k = kq*64 + (tid & 63);
  int strip = tid >> 6;
  float ec = 0.f;
  const float* er = enc_out + (size_t)b*Lmax*H2 + k;
  #pragma unroll 4
  for (int l = strip; l < Lmax; l += 4)
    ec = fmaf(att_s[l], er[(size_t)l*H2], ec);
  float dc = 0.f;
  const float* pr = prebuf + (size_t)b*Tt*H2 + k;
  for (int tp = strip; tp < t; tp += 4)
    dc = fmaf(datt_s[tp], pr[(size_t)tp*H2], dc);
  __syncthreads();
  red[tid] = ec; __syncthreads();
  if (tid < 64)
    cat_buf[b*3*H2 + H2 + kq*64 + tid] = red[tid] + red[64+tid] + red[128+tid] + red[192+tid];
  __syncthreads();
  red[tid] = dc; __syncthreads();
  if (tid < 64)
    cat_buf[b*3*H2 + 2*H2 + kq*64 + tid] = red[tid] + red[64+tid] + red[128+tid] + red[192+tid];
}

// ================= Wv bf16 pack =================
__global__ __launch_bounds__(256) void pack_wv_k(const float* __restrict__ Wv, unsigned short* __restrict__ Wbf)
{
  size_t i = ((size_t)blockIdx.x*256 + threadIdx.x)*4;
  #pragma unroll
  for (int j = 0; j < 4; ++j) {
    unsigned int u = __float_as_uint(Wv[i+j]);
    u = (u + 0x7fffu + ((u >> 16) & 1u)) >> 16;   // RNE
    Wbf[i+j] = (unsigned short)u;
  }
}

// ================= logits GEMM, bf16 weights: 64-col tiles, 500 blocks (2 blocks/CU) =================
__global__ __launch_bounds__(256) void wv_mm_bf_k(
    const float* __restrict__ cat_buf, const unsigned short* __restrict__ Wbf,
    const float* __restrict__ bv, float* __restrict__ logits)
{
  __shared__ float As[32][33];
  __shared__ float Wsh[32][65];
  int tid = threadIdx.x;
  int n0 = blockIdx.x*64;
  int tx = tid & 15, ty = tid >> 4;
  float acc[2][4] = {};
  for (int k0 = 0; k0 < 3*H2; k0 += 32) {
    #pragma unroll
    for (int i = 0; i < 4; ++i) {
      int a = tid*4+i;
      As[a>>5][a&31] = cat_buf[(size_t)(a>>5)*3*H2 + k0 + (a&31)];
    }
    #pragma unroll
    for (int j = 0; j < 4; ++j) {
      int a = j*256 + tid;              // 1024 uints: 32 rows x 32
      int row = a >> 5, c2 = (a & 31)*2;
      const unsigned int* wr = (const unsigned int*)(Wbf + (size_t)(k0+row)*Vv + n0);
      unsigned int u = wr[a & 31];
      Wsh[row][c2]   = bf2f(u & 0xffffu);
      Wsh[row][c2+1] = bf2f(u >> 16);
    }
    __syncthreads();
    #pragma unroll
    for (int kk = 0; kk < 32; ++kk) {
      float a0 = As[ty*2+0][kk], a1 = As[ty*2+1][kk];
      float w0 = Wsh[kk][tx*4+0], w1 = Wsh[kk][tx*4+1], w2 = Wsh[kk][tx*4+2], w3 = Wsh[kk][tx*4+3];
      acc[0][0]=fmaf(a0,w0,acc[0][0]); acc[0][1]=fmaf(a0,w1,acc[0][1]); acc[0][2]=fmaf(a0,w2,acc[0][2]); acc[0][3]=fmaf(a0,w3,acc[0][3]);
      acc[1][0]=fmaf(a1,w0,acc[1][0]); acc[1][1]=fmaf(a1,w1,acc[1][1]); acc[1][2]=fmaf(a1,w2,acc[1][2]); acc[1][3]=fmaf(a1,w3,acc[1][3]);
    }
    __syncthreads();
  }
  #pragma unroll
  for (int i = 0; i < 2; ++i)
    #pragma unroll
    for (int j = 0; j < 4; ++j) {
      int n = n0 + tx*4 + j;
      logits[(size_t)(ty*2+i)*Vv + n] = acc[i][j] + bv[n];
    }
}

// ================= logits GEMM, fp32 fallback =================
__global__ __launch_bounds__(256) void wv_mm_k(
    const float* __restrict__ cat_buf, const float* __restrict__ Wv,
    const float* __restrict__ bv, float* __restrict__ logits)
{
  __shared__ float As[32][33];
  __shared__ float Wsh[32][128];
  int tid = threadIdx.x;
  int n0 = blockIdx.x*128;
  int tx = tid & 31, ty = tid >> 5;
  float acc[4][4] = {};
  for (int k0 = 0; k0 < 3*H2; k0 += 32) {
    #pragma unroll
    for (int i = 0; i < 4; ++i) {
      int a = tid*4+i;
      As[a>>5][a&31] = cat_buf[(size_t)(a>>5)*3*H2 + k0 + (a&31)];
    }
    #pragma unroll
    for (int j = 0; j < 16; ++j) {
      int a = j*256+tid;
      Wsh[a>>7][a&127] = Wv[(size_t)(k0+(a>>7))*Vv + n0 + (a&127)];
    }
    __syncthreads();
    #pragma unroll
    for (int kk = 0; kk < 32; ++kk) {
      float a0 = As[ty*4+0][kk], a1 = As[ty*4+1][kk], a2 = As[ty*4+2][kk], a3 = As[ty*4+3][kk];
      float w0 = Wsh[kk][tx*4+0], w1 = Wsh[kk][tx*4+1], w2 = Wsh[kk][tx*4+2], w3 = Wsh[kk][tx*4+3];
      acc[0][0]=fmaf(a0,w0,acc[0][0]); acc[0][1]=fmaf(a0,w1,acc[0][1]); acc[0][2]=fmaf(a0,w2,acc[0][2]); acc[0][3]=fmaf(a0,w3,acc[0][3]);
      acc[1][0]=fmaf(a1,w0,acc[1][0]); acc[1][1]=fmaf(a1,w1,acc[1][1]); acc[1][2]=fmaf(a1,w2,acc[1][2]); acc[1][3]=fmaf(a1,w3,acc[1][3]);
      acc[2][0]=fmaf(a2,w0,acc[2][0]); acc[2][1]=fmaf(a2,w1,acc[2][1]); acc[2][2]=fmaf(a2,w2,acc[2][2]); acc[2][3]=fmaf(a2,w3,acc[2][3]);
      acc[3][0]=fmaf(a3,w0,acc[3][0]); acc[3][1]=fmaf(a3,w1,acc[3][1]); acc[3][2]=fmaf(a3,w2,acc[3][2]); acc[3][3]=fmaf(a3,w3,acc[3][3]);
    }
    __syncthreads();
  }
  #pragma unroll
  for (int i = 0; i < 4; ++i)
    #pragma unroll
    for (int j = 0; j < 4; ++j) {
      int n = n0 + tx*4 + j;
      logits[(size_t)(ty*4+i)*Vv + n] = acc[i][j] + bv[n];
    }
}

// ================= fused p_gen + softmax + pointer-scatter + argmax + loss =================
// block per b. p_gen computed here directly from cat_buf . Wp (no atomics).
__global__ __launch_bounds__(256) void final_k(
    const float* __restrict__ logits, const float* __restrict__ cat_buf,
    const float* __restrict__ Wp, const float* __restrict__ bps,
    const int* __restrict__ ev, const float* __restrict__ enc_att,
    const int* __restrict__ tgt_y, float* __restrict__ out,
    int* __restrict__ dec_in, int t)
{
  __shared__ float rf[256];
  __shared__ int   ri[256];
  __shared__ float tm[256];
  __shared__ int   ev_s[Lmax];
  __shared__ float pv_s[Lmax];
  __shared__ float m_sh, sc_sh, pg_sh;
  int b = blockIdx.x, tid = threadIdx.x;
  const float*  lr  = logits + (size_t)b*Vv;
  const float4* lr4 = (const float4*)lr;
  // p_gen: cat . Wp reduced over block
  {
    const float* catr = cat_buf + b*3*H2;
    float pgl = 0.f;
    for (int i = tid; i < 3*H2; i += 256) pgl += catr[i]*Wp[i];
    rf[tid] = pgl; __syncthreads();
    for (int s = 128; s > 0; s >>= 1) { if (tid < s) rf[tid] += rf[tid+s]; __syncthreads(); }
    if (tid == 0) pg_sh = sigf(rf[0] + bps[0]);
    __syncthreads();
  }
  // pass A: max
  float m = -1e30f;
  for (int i = tid; i < Vv/4; i += 256) {
    float4 v = lr4[i];
    m = fmaxf(m, fmaxf(fmaxf(v.x,v.y), fmaxf(v.z,v.w)));
  }
  rf[tid] = m; __syncthreads();
  for (int s = 128; s > 0; s >>= 1) { if (tid < s) rf[tid] = fmaxf(rf[tid], rf[tid+s]); __syncthreads(); }
  m = rf[0]; __syncthreads();
  // pass B: sum exp
  float ssum = 0.f;
  for (int i = tid; i < Vv/4; i += 256) {
    float4 v = lr4[i];
    ssum += expf(v.x-m) + expf(v.y-m) + expf(v.z-m) + expf(v.w-m);
  }
  rf[tid] = ssum; __syncthreads();
  for (int s = 128; s > 0; s >>= 1) { if (tid < s) rf[tid] += rf[tid+s]; __syncthreads(); }
  if (tid == 0) {
    sc_sh = (1.0f - pg_sh) / rf[0]; m_sh = m;
  }
  for (int l = tid; l < Lmax; l += 256) ev_s[l] = ev[b*Lmax + l];
  __syncthreads();
  float scale = sc_sh, pg = pg_sh; m = m_sh;
  for (int l = tid; l < Lmax; l += 256) pv_s[l] = pg * enc_att[b*Lmax + l];
  __syncthreads();
  // pass C: vocab argmax (first-index tiebreak; indices ascend per thread)
  float best = -1e30f; int bi = 0x7fffffff;
  for (int i = tid; i < Vv/4; i += 256) {
    float4 v = lr4[i];
    float p0 = expf(v.x-m)*scale, p1 = expf(v.y-m)*scale, p2 = expf(v.z-m)*scale, p3 = expf(v.w-m)*scale;
    int n = 4*i;
    if (p0 > best) { best = p0; bi = n; }
    if (p1 > best || (p1 == best && n+1 < bi)) { best = p1; bi = n+1; }
    if (p2 > best || (p2 == best && n+2 < bi)) { best = p2; bi = n+2; }
    if (p3 > best || (p3 == best && n+3 < bi)) { best = p3; bi = n+3; }
  }
  // touched pointer bins + target pointer mass
  int tgt = tgt_y[b*Tt + t];
  float ptm = 0.f;
  for (int l = tid; l < Lmax; l += 256) {
    int e = ev_s[l];
    float tot = 0.f;
    for (int l2 = 0; l2 < Lmax; ++l2) if (ev_s[l2] == e) tot += pv_s[l2];
    float vvv = tot + ((e < Vv) ? expf(lr[e]-m)*scale : 0.f);
    if (vvv > best || (vvv == best && e < bi)) { best = vvv; bi = e; }
    ptm += (e == tgt) ? pv_s[l] : 0.f;
  }
  rf[tid] = best; ri[tid] = bi; tm[tid] = ptm; __syncthreads();
  for (int s = 128; s > 0; s >>= 1) {
    if (tid < s) {
      float v2 = rf[tid+s]; int i2 = ri[tid+s];
      if (v2 > rf[tid] || (v2 == rf[tid] && i2 < ri[tid])) { rf[tid] = v2; ri[tid] = i2; }
      tm[tid] += tm[tid+s];
    }
    __syncthreads();
  }
  if (tid == 0) {
    int am = ri[0];
    float fr_tgt = expf(lr[tgt]-m)*scale + tm[0];
    float loss = (tgt != PAD_ID) ? -logf(fr_tgt + 1e-12f) : 0.0f;
    out[b*Tt + t] = (float)am;
    out[Bb*Tt + b*Tt + t] = loss;
    dec_in[b] = (am >= Vv) ? UNK_ID : am;
  }
}

extern "C" void kernel_launch(void* const* d_in, const int* in_sizes, int n_in,
                              void* d_out, int out_size, void* d_ws, size_t ws_size,
                              hipStream_t stream)
{
  const int*   x    = (const int*)  d_in[0];
  const int*   tgt  = (const int*)  d_in[2];
  const int*   ev   = (const int*)  d_in[3];
  const float* emb  = (const float*)d_in[5];
  const float* Wi_f = (const float*)d_in[6];
  const float* Wh_f = (const float*)d_in[7];
  const float* b_f  = (const float*)d_in[8];
  const float* Wi_b = (const float*)d_in[9];
  const float* Wh_b = (const float*)d_in[10];
  const float* b_b  = (const float*)d_in[11];
  const float* dWi  = (const float*)d_in[12];
  const float* dWh  = (const float*)d_in[13];
  const float* db   = (const float*)d_in[14];
  const float* Wea  = (const float*)d_in[15];
  const float* Wda  = (const float*)d_in[16];
  const float* Wv   = (const float*)d_in[17];
  const float* bv   = (const float*)d_in[18];
  const float* Wp   = (const float*)d_in[19];
  const float* bp   = (const float*)d_in[20];
  float* out = (float*)d_out;

  float* ws = (float*)d_ws;
  size_t off = 0;
  float* enc_out = ws + off; off += (size_t)Bb*Lmax*H2;     // 13,107,200
  float* c_buf   = ws + off; off += 2*Bb*Hh;                // 32,768
  float4* wip    = (float4*)(ws + off); off += 2*256*512*4; // 1,048,576
  float4* whp    = (float4*)(ws + off); off += 2*512*512*4; // 2,097,152
  float4* biasp  = (float4*)(ws + off); off += 2*512*4;     // 4,096
  float* cat_buf = ws + off; off += Bb*3*H2;
  float* prebuf  = ws + off; off += (size_t)Bb*Tt*H2;
  float* accumA  = ws + off; off += Bb*Lmax;
  float* accumB  = ws + off; off += Bb*Lmax;
  float* zi_buf  = ws + off; off += Bb*3*H2;
  float* zh_buf  = ws + off; off += (size_t)2*Bb*3*H2;      // 2 K-partials
  float* qp      = ws + off; off += (size_t)4*Bb*H2;        // 4 K-partials
  float* qdp     = ws + off; off += (size_t)4*Bb*H2;
  float* esc     = ws + off; off += Bb*Lmax;
  float* enc_att = ws + off; off += Bb*Lmax;
  float* ed      = ws + off; off += Bb*Tt;
  float* logits  = ws + off; off += (size_t)Bb*Vv;
  int*   dec_in  = (int*)(ws + off); off += 32;
  unsigned short* Wbf = (unsigned short*)(ws + off);
  size_t need_bf16 = off*4 + (size_t)3*H2*Vv*2;             // bytes
  int use_bf16 = (ws_size >= need_bf16 + (64u<<10)) ? 1 : 0;

  // one-time packs (re-done every call: ws is re-poisoned)
  pack_enc_k<<<2048,256,0,stream>>>(Wi_f,Wh_f,b_f,Wi_b,Wh_b,b_b,wip,whp,biasp);
  if (use_bf16) pack_wv_k<<<96000,256,0,stream>>>(Wv, Wbf);

  for (int t = 0; t < Lmax; ++t)
    enc_step2_k<<<256,512,0,stream>>>(wip,whp,biasp,emb,x,c_buf,enc_out,t);

  init_dec_k<<<128,256,0,stream>>>(enc_out,cat_buf,dec_in);

  for (int t = 0; t < Tt; ++t) {
    float* ar = (t & 1) ? accumB : accumA;   // read (old running sums); unused at t==0
    float* aw = (t & 1) ? accumA : accumB;   // write (new running sums)
    gru_mm_k  <<<768,256,0,stream>>>(emb,dec_in,cat_buf,dWi,dWh,db,zi_buf,zh_buf);
    gru_comb_k<<<128,256,0,stream>>>(zi_buf,zh_buf,cat_buf,prebuf,t);
    qq_k      <<<512,256,0,stream>>>(cat_buf,Wea,Wda,qp,qdp);
    att_sc_k  <<<3712,256,0,stream>>>(qp,qdp,enc_out,prebuf,esc,ed,t);
    ctx_norm_k<<<512,256,0,stream>>>(esc,ar,aw,enc_att,ed,enc_out,prebuf,cat_buf,t);
    if (use_bf16) wv_mm_bf_k<<<500,256,0,stream>>>(cat_buf,Wbf,bv,logits);
    else          wv_mm_k   <<<250,256,0,stream>>>(cat_buf,Wv,bv,logits);
    final_k   <<<32,256,0,stream>>>(logits,cat_buf,Wp,bp,ev,enc_att,tgt,out,dec_in,t);
  }
}

// Round 2
// 34718.015 us; speedup vs baseline: 1.2654x; 1.0700x over previous
//
#include <hip/hip_runtime.h>
#include <math.h>

#define Bb 32
#define Lmax 400
#define Tt 64
#define Ee 256
#define Hh 512
#define H2 1024
#define Vv 32000
#define OOV 100
#define VX (Vv+OOV)
#define PAD_ID 0
#define UNK_ID 1
#define START_ID 2

__device__ __forceinline__ float sigf(float x){ return 1.0f/(1.0f+expf(-x)); }
__device__ __forceinline__ float bf2f(unsigned int u){ u <<= 16; return __uint_as_float(u); }

// ================= encoder weight packing =================
// wip[(dir*256+k)*512+n] = float4{Wi[k][g*512+n], g=0..3}; whp analog (K=512); bp[dir*512+n]=bias gates
__global__ __launch_bounds__(256) void pack_enc_k(
    const float* __restrict__ Wi_f, const float* __restrict__ Wh_f, const float* __restrict__ b_f,
    const float* __restrict__ Wi_b, const float* __restrict__ Wh_b, const float* __restrict__ b_b,
    float4* __restrict__ wip, float4* __restrict__ whp, float4* __restrict__ bp)
{
  int o = blockIdx.x*256 + threadIdx.x;
  if (o < 2*256*512) {
    int n = o & 511; int k = (o >> 9) & 255; int dir = o >> 17;
    const float* W = dir ? Wi_b : Wi_f;
    wip[o] = make_float4(W[k*2048+n], W[k*2048+512+n], W[k*2048+1024+n], W[k*2048+1536+n]);
  }
  if (o < 2*512*512) {
    int n = o & 511; int k = (o >> 9) & 511; int dir = o >> 18;
    const float* W = dir ? Wh_b : Wh_f;
    whp[o] = make_float4(W[k*2048+n], W[k*2048+512+n], W[k*2048+1024+n], W[k*2048+1536+n]);
  }
  if (o < 2*512) {
    int n = o & 511; int dir = o >> 9;
    const float* bs = dir ? b_b : b_f;
    bp[o] = make_float4(bs[n], bs[512+n], bs[1024+n], bs[1536+n]);
  }
}

// FMA helper: acc += h.{x,y,z,w} * w{0..3} (float4 gate-wise)
#define FMA16(ACC, HV, W0, W1, W2, W3) \
  ACC.x = fmaf(HV.x, W0.x, ACC.x); ACC.y = fmaf(HV.x, W0.y, ACC.y); \
  ACC.z = fmaf(HV.x, W0.z, ACC.z); ACC.w = fmaf(HV.x, W0.w, ACC.w); \
  ACC.x = fmaf(HV.y, W1.x, ACC.x); ACC.y = fmaf(HV.y, W1.y, ACC.y); \
  ACC.z = fmaf(HV.y, W1.z, ACC.z); ACC.w = fmaf(HV.y, W1.w, ACC.w); \
  ACC.x = fmaf(HV.z, W2.x, ACC.x); ACC.y = fmaf(HV.z, W2.y, ACC.y); \
  ACC.z = fmaf(HV.z, W2.z, ACC.z); ACC.w = fmaf(HV.z, W2.w, ACC.w); \
  ACC.x = fmaf(HV.w, W3.x, ACC.x); ACC.y = fmaf(HV.w, W3.y, ACC.y); \
  ACC.z = fmaf(HV.w, W3.z, ACC.z); ACC.w = fmaf(HV.w, W3.w, ACC.w);

// ================= encoder step v3: LDS-staged h/x (transposed [k4][b]), 4b/thread =================
// grid 256 = dir(2) x ngroup(128, 4 n each); block 512 = ks(16) x nl(4) x bq(8)
// thread (bq,nl,ks): 4 b (b0=bq*4), 1 n (ng*4+nl), k-slice (wh: 32k, wi: 16k)
__global__ __launch_bounds__(512) void enc_step3_k(
    const float4* __restrict__ wip, const float4* __restrict__ whp, const float4* __restrict__ bp,
    const float* __restrict__ emb, const int* __restrict__ x,
    float* __restrict__ c_buf, float* __restrict__ enc_out, int t)
{
  __shared__ float4 wi_s[256*4];     // [k*4 + nl] : gates f4 for (k, n-local)
  __shared__ float4 wh_s[512*4];
  __shared__ float4 hs2[128*33];     // [k4*33 + b] : h[4k4+j][b] over j
  __shared__ float4 xr_red[64*33];   // xs2 [k4*33+b] overlaid with red [ks*132 + bn] (both 2112 f4)
  int bx = blockIdx.x;
  int dir = bx >> 7, ng = bx & 127;
  int tid = threadIdx.x;
  int ks = tid >> 5;
  int r  = tid & 31;
  int bq = r & 7, nl = r >> 3;
  int b0 = bq*4;
  int tt = dir ? (Lmax-1-t) : t;

  // ---- stage weights (from packed global, coalesced) ----
  for (int i = tid; i < 1024; i += 512) {
    int k = i >> 2, l = i & 3;
    wi_s[i] = wip[(dir*256 + k)*512 + ng*4 + l];
  }
  for (int i = tid; i < 2048; i += 512) {
    int k = i >> 2, l = i & 3;
    wh_s[i] = whp[(dir*512 + k)*512 + ng*4 + l];
  }
  // ---- stage x (coalesced per-emb-row reads, transposed write) ----
  {
    int sb = tid >> 4, kb = tid & 15;
    int tok = x[sb*Lmax + tt];
    const float4* er = (const float4*)(emb + (size_t)tok*Ee);
    #pragma unroll
    for (int i = 0; i < 4; ++i) {
      int k4 = kb + 16*i;
      xr_red[k4*33 + sb] = er[k4];
    }
  }
  // ---- stage h(t-1) ----
  if (t > 0) {
    int pt = dir ? (tt+1) : (tt-1);
    int sb = tid >> 4, kb = tid & 15;
    const float4* hb = (const float4*)(enc_out + ((size_t)sb*Lmax + pt)*H2 + dir*Hh);
    #pragma unroll
    for (int i = 0; i < 8; ++i) {
      int k4 = kb + 16*i;
      hs2[k4*33 + sb] = hb[k4];
    }
  }
  __syncthreads();

  float4 acc0 = make_float4(0.f,0.f,0.f,0.f);
  float4 acc1 = acc0, acc2 = acc0, acc3 = acc0;
  if (t > 0) {
    int k4b = ks*8;
    #pragma unroll
    for (int kk = 0; kk < 8; ++kk) {
      int k4 = k4b + kk;
      float4 w0 = wh_s[(k4*4+0)*4 + nl];
      float4 w1 = wh_s[(k4*4+1)*4 + nl];
      float4 w2 = wh_s[(k4*4+2)*4 + nl];
      float4 w3 = wh_s[(k4*4+3)*4 + nl];
      float4 h0 = hs2[k4*33 + b0+0];
      float4 h1 = hs2[k4*33 + b0+1];
      float4 h2 = hs2[k4*33 + b0+2];
      float4 h3 = hs2[k4*33 + b0+3];
      FMA16(acc0, h0, w0, w1, w2, w3);
      FMA16(acc1, h1, w0, w1, w2, w3);
      FMA16(acc2, h2, w0, w1, w2, w3);
      FMA16(acc3, h3, w0, w1, w2, w3);
    }
  }
  {
    int k4b = ks*4;
    #pragma unroll
    for (int kk = 0; kk < 4; ++kk) {
      int k4 = k4b + kk;
      float4 w0 = wi_s[(k4*4+0)*4 + nl];
      float4 w1 = wi_s[(k4*4+1)*4 + nl];
      float4 w2 = wi_s[(k4*4+2)*4 + nl];
      float4 w3 = wi_s[(k4*4+3)*4 + nl];
      float4 h0 = xr_red[k4*33 + b0+0];
      float4 h1 = xr_red[k4*33 + b0+1];
      float4 h2 = xr_red[k4*33 + b0+2];
      float4 h3 = xr_red[k4*33 + b0+3];
      FMA16(acc0, h0, w0, w1, w2, w3);
      FMA16(acc1, h1, w0, w1, w2, w3);
      FMA16(acc2, h2, w0, w1, w2, w3);
      FMA16(acc3, h3, w0, w1, w2, w3);
    }
  }
  __syncthreads();   // all xs2 reads done; xr_red becomes red
  // red[ks][bn], bn = b*4 + nl = 16bq + 4bi + nl, row stride 132 f4
  {
    int base = ks*132 + 16*bq + nl;
    xr_red[base + 0]  = acc0;
    xr_red[base + 4]  = acc1;
    xr_red[base + 8]  = acc2;
    xr_red[base + 12] = acc3;
  }
  __syncthreads();
  if (tid < 128) {
    int bn = tid;
    float4 s = xr_red[bn];
    #pragma unroll
    for (int kr = 1; kr < 16; ++kr) {
      float4 v = xr_red[kr*132 + bn];
      s.x += v.x; s.y += v.y; s.z += v.z; s.w += v.w;
    }
    int b = bn >> 2, nl2 = bn & 3, n = ng*4 + nl2;
    float4 bb = bp[dir*512 + n];
    float zi = s.x + bb.x;
    float zf = s.y + bb.y;
    float zg = s.z + bb.z;
    float zo = s.w + bb.w;
    int ci = (dir*32 + b)*Hh + n;
    float cv = (t==0) ? 0.f : c_buf[ci];
    float cn = sigf(zf)*cv + sigf(zi)*tanhf(zg);
    float hn = sigf(zo)*tanhf(cn);
    c_buf[ci] = cn;
    enc_out[((size_t)b*Lmax + tt)*H2 + dir*Hh + n] = hn;
  }
}

// ================= decoder init =================
__global__ __launch_bounds__(256) void init_dec_k(
    const float* __restrict__ enc_out, float* __restrict__ cat_buf,
    float* __restrict__ h0, int* __restrict__ dec_in)
{
  int idx = blockIdx.x*256 + threadIdx.x;
  if (idx < Bb*H2) {
    int b = idx >> 10, n = idx & 1023;
    float v = (n < Hh) ? enc_out[((size_t)b*Lmax + (Lmax-1))*H2 + n]
                       : enc_out[(size_t)b*Lmax*H2 + n];
    cat_buf[b*3*H2 + n] = v;
    h0[b*H2 + n] = v;
  }
  if (idx < Bb) dec_in[idx] = START_ID;
}

// ================= GRU matmuls: K-split x2 for occupancy (768 blocks = 12 waves/CU) =================
// grid 768 = ng(48 x 64n) x bg(8 x 4b) x kq(2); block 256 = nl(64) x bl(4)
__global__ __launch_bounds__(256) void gru_mm_k(
    const float* __restrict__ emb, const int* __restrict__ dec_in,
    const float* __restrict__ cat_buf, const float* __restrict__ Wi,
    const float* __restrict__ Wh, const float* __restrict__ bias,
    float* __restrict__ zi_buf, float* __restrict__ zh_buf)
{
  int bx = blockIdx.x;
  int ng = bx % 48; int bg = (bx / 48) & 7; int kq = bx / 384;
  int nl = threadIdx.x & 63, bl = threadIdx.x >> 6;
  int n = ng*64 + nl, b = bg*4 + bl;
  const float* hr = cat_buf + b*3*H2;
  float zh = 0.f;
  int k0 = kq*512;
  #pragma unroll 4
  for (int k = k0; k < k0+512; ++k)
    zh = fmaf(hr[k], Wh[(size_t)k*3*H2 + n], zh);
  zh_buf[(size_t)(kq*Bb + b)*3*H2 + n] = zh;
  if (kq == 0) {
    const float* er = emb + (size_t)dec_in[b]*Ee;
    float zi = bias[n];
    #pragma unroll 4
    for (int k = 0; k < Ee; ++k)
      zi = fmaf(er[k], Wi[(size_t)k*3*H2 + n], zi);
    zi_buf[b*3*H2 + n] = zi;
  }
}

// ================= fused GRU-combine + attention queries =================
// grid 512 = ng(16 x 64n) x bg(8 x 4b) x kq(4); block 256 = nl(64) x bl(4)
// Phase 1: each block recomputes h[b][k] for its 4 b x kq-quarter (from zi/zh, hold from
// h0/prebuf[t-1] -> no cat_buf race); ng==0 blocks write cat_buf h-region + prebuf[t].
// Phase 2: query partials over the kq-quarter.
__global__ __launch_bounds__(256) void qq_f_k(
    const float* __restrict__ zi_buf, const float* __restrict__ zh_buf,
    const float* __restrict__ h0, float* __restrict__ prebuf,
    const float* __restrict__ Wea, const float* __restrict__ Wda,
    float* __restrict__ cat_buf, float* __restrict__ qp, float* __restrict__ qdp, int t)
{
  __shared__ float hsq[4*260];
  int bx = blockIdx.x;
  int ng = bx & 15, bg = (bx >> 4) & 7, kq = bx >> 7;
  int nl = threadIdx.x & 63, bl = threadIdx.x >> 6;
  int n = ng*64 + nl, b = bg*4 + bl;
  const float* zi  = zi_buf + b*3*H2;
  const float* zh0 = zh_buf + (size_t)b*3*H2;
  const float* zh1 = zh_buf + (size_t)(Bb + b)*3*H2;
  #pragma unroll
  for (int i = 0; i < 4; ++i) {
    int kk = nl + 64*i, k = kq*256 + kk;
    float zhr = zh0[k]      + zh1[k];
    float zhz = zh0[H2+k]   + zh1[H2+k];
    float zhg = zh0[2*H2+k] + zh1[2*H2+k];
    float rr = sigf(zi[k] + zhr);
    float zz = sigf(zi[H2+k] + zhz);
    float nn = tanhf(zi[2*H2+k] + rr*zhg);
    float hold = (t == 0) ? h0[b*H2 + k]
                          : prebuf[((size_t)b*Tt + (t-1))*H2 + k];
    float h = (1.0f - zz)*nn + zz*hold;
    hsq[bl*260 + kk] = h;
    if (ng == 0) {
      cat_buf[b*3*H2 + k] = h;
      prebuf[((size_t)b*Tt + t)*H2 + k] = h;
    }
  }
  __syncthreads();
  const float* hr = hsq + bl*260;
  const float* wa = Wea + (size_t)(kq*256)*H2 + n;
  const float* wd = Wda + (size_t)(kq*256)*H2 + n;
  float s1 = 0.f, s2 = 0.f;
  #pragma unroll 4
  for (int kk = 0; kk < 256; ++kk) {
    float hv = hr[kk];
    s1 = fmaf(hv, wa[(size_t)kk*H2], s1);
    s2 = fmaf(hv, wd[(size_t)kk*H2], s2);
  }
  qp [(size_t)(kq*Bb + b)*H2 + n] = s1;
  qdp[(size_t)(kq*Bb + b)*H2 + n] = s2;
}

// ================= sum the 4 query K-partials (tiny) =================
__global__ __launch_bounds__(256) void qsum_k(
    const float* __restrict__ qp, const float* __restrict__ qdp,
    float* __restrict__ q, float* __restrict__ qd)
{
  int i = blockIdx.x*256 + threadIdx.x;   // f4 index, 8192 total
  const float4* p  = (const float4*)qp;
  const float4* pd = (const float4*)qdp;
  float4 a = p[i], b1 = p[8192+i], c = p[16384+i], d = p[24576+i];
  ((float4*)q)[i] = make_float4(a.x+b1.x+c.x+d.x, a.y+b1.y+c.y+d.y,
                                a.z+b1.z+c.z+d.z, a.w+b1.w+c.w+d.w);
  float4 e = pd[i], f = pd[8192+i], g = pd[16384+i], h = pd[24576+i];
  ((float4*)qd)[i] = make_float4(e.x+f.x+g.x+h.x, e.y+f.y+g.y+h.y,
                                 e.z+f.z+g.z+h.z, e.w+f.w+g.w+h.w);
}

// ================= attention scores (float4) =================
__global__ __launch_bounds__(256) void att_sc_k(
    const float* __restrict__ q, const float* __restrict__ qd,
    const float* __restrict__ enc_out, const float* __restrict__ prebuf,
    float* __restrict__ esc, float* __restrict__ ed, int t)
{
  int w = blockIdx.x*4 + (threadIdx.x >> 6);
  int lane = threadIdx.x & 63;
  int b = w / 464;
  int row = w - b*464;
  if (b >= Bb) return;
  float s = 0.0f;
  if (row < Lmax) {
    const float4* qr = (const float4*)(q + b*H2);
    const float4* er = (const float4*)(enc_out + ((size_t)b*Lmax + row)*H2);
    #pragma unroll
    for (int j = 0; j < 4; ++j) {
      float4 a = qr[lane + 64*j], e = er[lane + 64*j];
      s += a.x*e.x + a.y*e.y + a.z*e.z + a.w*e.w;
    }
  } else {
    int tp = row - Lmax;
    if (tp >= t) { if (lane==0) ed[b*Tt+tp] = 0.0f; return; }
    const float4* qr = (const float4*)(qd + b*H2);
    const float4* pr = (const float4*)(prebuf + ((size_t)b*Tt + tp)*H2);
    #pragma unroll
    for (int j = 0; j < 4; ++j) {
      float4 a = qr[lane + 64*j], e = pr[lane + 64*j];
      s += a.x*e.x + a.y*e.y + a.z*e.z + a.w*e.w;
    }
  }
  for (int o = 32; o > 0; o >>= 1) s += __shfl_xor(s, o);
  if (lane == 0) { if (row < Lmax) esc[b*Lmax+row] = s; else ed[b*Tt + (row-Lmax)] = s; }
}

// ================= fused temporal-normalize + intra-dec softmax + contexts =================
// grid 512 = b(32) x kq(16 x 64k); block 256 = klane(64) x lstrip(4)
__global__ __launch_bounds__(256) void ctx_norm_k(
    const float* __restrict__ esc, const float* __restrict__ acc_r, float* __restrict__ acc_w,
    float* __restrict__ enc_att, const float* __restrict__ ed,
    const float* __restrict__ enc_out, const float* __restrict__ prebuf,
    float* __restrict__ cat_buf, int t)
{
  __shared__ float att_s[Lmax];
  __shared__ float datt_s[Tt];
  __shared__ float red[256];
  int b = blockIdx.x >> 4, kq = blockIdx.x & 15;
  int tid = threadIdx.x;
  float loc = 0.f;
  for (int l = tid; l < Lmax; l += 256) {
    float ee = expf(esc[b*Lmax + l]);
    float a  = (t == 0) ? 0.f : acc_r[b*Lmax + l];
    float un = (t == 0) ? ee : ee / (a + 1e-10f);
    att_s[l] = un;
    loc += un;
    if (kq == 0) acc_w[b*Lmax + l] = a + ee;
  }
  red[tid] = loc; __syncthreads();
  for (int s = 128; s > 0; s >>= 1) { if (tid < s) red[tid] += red[tid+s]; __syncthreads(); }
  float inv = 1.0f / red[0];
  for (int l = tid; l < Lmax; l += 256) {
    float v = att_s[l] * inv;
    att_s[l] = v;
    if (kq == 0) enc_att[b*Lmax + l] = v;
  }
  if (tid < 64 && t > 0) {
    float v = (tid < t) ? ed[b*Tt + tid] : -INFINITY;
    float m = v;
    for (int o = 32; o > 0; o >>= 1) m = fmaxf(m, __shfl_xor(m, o));
    float p = (tid < t) ? expf(v - m) : 0.f;
    float ss = p;
    for (int o = 32; o > 0; o >>= 1) ss += __shfl_xor(ss, o);
    datt_s[tid] = p / ss;
  }
  __syncthreads();
  int k = kq*64 + (tid & 63);
  int strip = tid >> 6;
  float ec = 0.f;
  const float* er = enc_out + (size_t)b*Lmax*H2 + k;
  #pragma unroll 4
  for (int l = strip; l < Lmax; l += 4)
    ec = fmaf(att_s[l], er[(size_t)l*H2], ec);
  float dc = 0.f;
  const float* pr = prebuf + (size_t)b*Tt*H2 + k;
  for (int tp = strip; tp < t; tp += 4)
    dc = fmaf(datt_s[tp], pr[(size_t)tp*H2], dc);
  __syncthreads();
  red[tid] = ec; __syncthreads();
  if (tid < 64)
    cat_buf[b*3*H2 + H2 + kq*64 + tid] = red[tid] + red[64+tid] + red[128+tid] + red[192+tid];
  __syncthreads();
  red[tid] = dc; __syncthreads();
  if (tid < 64)
    cat_buf[b*3*H2 + 2*H2 + kq*64 + tid] = red[tid] + red[64+tid] + red[128+tid] + red[192+tid];
}

// ================= Wv bf16 pack =================
__global__ __launch_bounds__(256) void pack_wv_k(const float* __restrict__ Wv, unsigned short* __restrict__ Wbf)
{
  size_t i = ((size_t)blockIdx.x*256 + threadIdx.x)*4;
  #pragma unroll
  for (int j = 0; j < 4; ++j) {
    unsigned int u = __float_as_uint(Wv[i+j]);
    u = (u + 0x7fffu + ((u >> 16) & 1u)) >> 16;   // RNE
    Wbf[i+j] = (unsigned short)u;
  }
}

// ================= logits GEMM, bf16 weights: 64-col tiles, 500 blocks =================
__global__ __launch_bounds__(256) void wv_mm_bf_k(
    const float* __restrict__ cat_buf, const unsigned short* __restrict__ Wbf,
    const float* __restrict__ bv, float* __restrict__ logits)
{
  __shared__ float As[32][33];
  __shared__ float Wsh[32][65];
  int tid = threadIdx.x;
  int n0 = blockIdx.x*64;
  int tx = tid & 15, ty = tid >> 4;
  float acc[2][4] = {};
  for (int k0 = 0; k0 < 3*H2; k0 += 32) {
    #pragma unroll
    for (int i = 0; i < 4; ++i) {
      int a = tid*4+i;
      As[a>>5][a&31] = cat_buf[(size_t)(a>>5)*3*H2 + k0 + (a&31)];
    }
    #pragma unroll
    for (int j = 0; j < 4; ++j) {
      int a = j*256 + tid;
      int row = a >> 5, c2 = (a & 31)*2;
      const unsigned int* wr = (const unsigned int*)(Wbf + (size_t)(k0+row)*Vv + n0);
      unsigned int u = wr[a & 31];
      Wsh[row][c2]   = bf2f(u & 0xffffu);
      Wsh[row][c2+1] = bf2f(u >> 16);
    }
    __syncthreads();
    #pragma unroll
    for (int kk = 0; kk < 32; ++kk) {
      float a0 = As[ty*2+0][kk], a1 = As[ty*2+1][kk];
      float w0 = Wsh[kk][tx*4+0], w1 = Wsh[kk][tx*4+1], w2 = Wsh[kk][tx*4+2], w3 = Wsh[kk][tx*4+3];
      acc[0][0]=fmaf(a0,w0,acc[0][0]); acc[0][1]=fmaf(a0,w1,acc[0][1]); acc[0][2]=fmaf(a0,w2,acc[0][2]); acc[0][3]=fmaf(a0,w3,acc[0][3]);
      acc[1][0]=fmaf(a1,w0,acc[1][0]); acc[1][1]=fmaf(a1,w1,acc[1][1]); acc[1][2]=fmaf(a1,w2,acc[1][2]); acc[1][3]=fmaf(a1,w3,acc[1][3]);
    }
    __syncthreads();
  }
  #pragma unroll
  for (int i = 0; i < 2; ++i)
    #pragma unroll
    for (int j = 0; j < 4; ++j) {
      int n = n0 + tx*4 + j;
      logits[(size_t)(ty*2+i)*Vv + n] = acc[i][j] + bv[n];
    }
}

// ================= logits GEMM, fp32 fallback =================
__global__ __launch_bounds__(256) void wv_mm_k(
    const float* __restrict__ cat_buf, const float* __restrict__ Wv,
    const float* __restrict__ bv, float* __restrict__ logits)
{
  __shared__ float As[32][33];
  __shared__ float Wsh[32][128];
  int tid = threadIdx.x;
  int n0 = blockIdx.x*128;
  int tx = tid & 31, ty = tid >> 5;
  float acc[4][4] = {};
  for (int k0 = 0; k0 < 3*H2; k0 += 32) {
    #pragma unroll
    for (int i = 0; i < 4; ++i) {
      int a = tid*4+i;
      As[a>>5][a&31] = cat_buf[(size_t)(a>>5)*3*H2 + k0 + (a&31)];
    }
    #pragma unroll
    for (int j = 0; j < 16; ++j) {
      int a = j*256+tid;
      Wsh[a>>7][a&127] = Wv[(size_t)(k0+(a>>7))*Vv + n0 + (a&127)];
    }
    __syncthreads();
    #pragma unroll
    for (int kk = 0; kk < 32; ++kk) {
      float a0 = As[ty*4+0][kk], a1 = As[ty*4+1][kk], a2 = As[ty*4+2][kk], a3 = As[ty*4+3][kk];
      float w0 = Wsh[kk][tx*4+0], w1 = Wsh[kk][tx*4+1], w2 = Wsh[kk][tx*4+2], w3 = Wsh[kk][tx*4+3];
      acc[0][0]=fmaf(a0,w0,acc[0][0]); acc[0][1]=fmaf(a0,w1,acc[0][1]); acc[0][2]=fmaf(a0,w2,acc[0][2]); acc[0][3]=fmaf(a0,w3,acc[0][3]);
      acc[1][0]=fmaf(a1,w0,acc[1][0]); acc[1][1]=fmaf(a1,w1,acc[1][1]); acc[1][2]=fmaf(a1,w2,acc[1][2]); acc[1][3]=fmaf(a1,w3,acc[1][3]);
      acc[2][0]=fmaf(a2,w0,acc[2][0]); acc[2][1]=fmaf(a2,w1,acc[2][1]); acc[2][2]=fmaf(a2,w2,acc[2][2]); acc[2][3]=fmaf(a2,w3,acc[2][3]);
      acc[3][0]=fmaf(a3,w0,acc[3][0]); acc[3][1]=fmaf(a3,w1,acc[3][1]); acc[3][2]=fmaf(a3,w2,acc[3][2]); acc[3][3]=fmaf(a3,w3,acc[3][3]);
    }
    __syncthreads();
  }
  #pragma unroll
  for (int i = 0; i < 4; ++i)
    #pragma unroll
    for (int j = 0; j < 4; ++j) {
      int n = n0 + tx*4 + j;
      logits[(size_t)(ty*4+i)*Vv + n] = acc[i][j] + bv[n];
    }
}

// ================= fused p_gen + softmax + pointer-scatter + argmax + loss =================
__global__ __launch_bounds__(256) void final_k(
    const float* __restrict__ logits, const float* __restrict__ cat_buf,
    const float* __restrict__ Wp, const float* __restrict__ bps,
    const int* __restrict__ ev, const float* __restrict__ enc_att,
    const int* __restrict__ tgt_y, float* __restrict__ out,
    int* __restrict__ dec_in, int t)
{
  __shared__ float rf[256];
  __shared__ int   ri[256];
  __shared__ float tm[256];
  __shared__ int   ev_s[Lmax];
  __shared__ float pv_s[Lmax];
  __shared__ float m_sh, sc_sh, pg_sh;
  int b = blockIdx.x, tid = threadIdx.x;
  const float*  lr  = logits + (size_t)b*Vv;
  const float4* lr4 = (const float4*)lr;
  {
    const float* catr = cat_buf + b*3*H2;
    float pgl = 0.f;
    for (int i = tid; i < 3*H2; i += 256) pgl += catr[i]*Wp[i];
    rf[tid] = pgl; __syncthreads();
    for (int s = 128; s > 0; s >>= 1) { if (tid < s) rf[tid] += rf[tid+s]; __syncthreads(); }
    if (tid == 0) pg_sh = sigf(rf[0] + bps[0]);
    __syncthreads();
  }
  float m = -1e30f;
  for (int i = tid; i < Vv/4; i += 256) {
    float4 v = lr4[i];
    m = fmaxf(m, fmaxf(fmaxf(v.x,v.y), fmaxf(v.z,v.w)));
  }
  rf[tid] = m; __syncthreads();
  for (int s = 128; s > 0; s >>= 1) { if (tid < s) rf[tid] = fmaxf(rf[tid], rf[tid+s]); __syncthreads(); }
  m = rf[0]; __syncthreads();
  float ssum = 0.f;
  for (int i = tid; i < Vv/4; i += 256) {
    float4 v = lr4[i];
    ssum += expf(v.x-m) + expf(v.y-m) + expf(v.z-m) + expf(v.w-m);
  }
  rf[tid] = ssum; __syncthreads();
  for (int s = 128; s > 0; s >>= 1) { if (tid < s) rf[tid] += rf[tid+s]; __syncthreads(); }
  if (tid == 0) {
    sc_sh = (1.0f - pg_sh) / rf[0]; m_sh = m;
  }
  for (int l = tid; l < Lmax; l += 256) ev_s[l] = ev[b*Lmax + l];
  __syncthreads();
  float scale = sc_sh, pg = pg_sh; m = m_sh;
  for (int l = tid; l < Lmax; l += 256) pv_s[l] = pg * enc_att[b*Lmax + l];
  __syncthreads();
  float best = -1e30f; int bi = 0x7fffffff;
  for (int i = tid; i < Vv/4; i += 256) {
    float4 v = lr4[i];
    float p0 = expf(v.x-m)*scale, p1 = expf(v.y-m)*scale, p2 = expf(v.z-m)*scale, p3 = expf(v.w-m)*scale;
    int n = 4*i;
    if (p0 > best) { best = p0; bi = n; }
    if (p1 > best || (p1 == best && n+1 < bi)) { best = p1; bi = n+1; }
    if (p2 > best || (p2 == best && n+2 < bi)) { best = p2; bi = n+2; }
    if (p3 > best || (p3 == best && n+3 < bi)) { best = p3; bi = n+3; }
  }
  int tgt = tgt_y[b*Tt + t];
  float ptm = 0.f;
  for (int l = tid; l < Lmax; l += 256) {
    int e = ev_s[l];
    float tot = 0.f;
    for (int l2 = 0; l2 < Lmax; ++l2) if (ev_s[l2] == e) tot += pv_s[l2];
    float vvv = tot + ((e < Vv) ? expf(lr[e]-m)*scale : 0.f);
    if (vvv > best || (vvv == best && e < bi)) { best = vvv; bi = e; }
    ptm += (e == tgt) ? pv_s[l] : 0.f;
  }
  rf[tid] = best; ri[tid] = bi; tm[tid] = ptm; __syncthreads();
  for (int s = 128; s > 0; s >>= 1) {
    if (tid < s) {
      float v2 = rf[tid+s]; int i2 = ri[tid+s];
      if (v2 > rf[tid] || (v2 == rf[tid] && i2 < ri[tid])) { rf[tid] = v2; ri[tid] = i2; }
      tm[tid] += tm[tid+s];
    }
    __syncthreads();
  }
  if (tid == 0) {
    int am = ri[0];
    float fr_tgt = expf(lr[tgt]-m)*scale + tm[0];
    float loss = (tgt != PAD_ID) ? -logf(fr_tgt + 1e-12f) : 0.0f;
    out[b*Tt + t] = (float)am;
    out[Bb*Tt + b*Tt + t] = loss;
    dec_in[b] = (am >= Vv) ? UNK_ID : am;
  }
}

extern "C" void kernel_launch(void* const* d_in, const int* in_sizes, int n_in,
                              void* d_out, int out_size, void* d_ws, size_t ws_size,
                              hipStream_t stream)
{
  const int*   x    = (const int*)  d_in[0];
  const int*   tgt  = (const int*)  d_in[2];
  const int*   ev   = (const int*)  d_in[3];
  const float* emb  = (const float*)d_in[5];
  const float* Wi_f = (const float*)d_in[6];
  const float* Wh_f = (const float*)d_in[7];
  const float* b_f  = (const float*)d_in[8];
  const float* Wi_b = (const float*)d_in[9];
  const float* Wh_b = (const float*)d_in[10];
  const float* b_b  = (const float*)d_in[11];
  const float* dWi  = (const float*)d_in[12];
  const float* dWh  = (const float*)d_in[13];
  const float* db   = (const float*)d_in[14];
  const float* Wea  = (const float*)d_in[15];
  const float* Wda  = (const float*)d_in[16];
  const float* Wv   = (const float*)d_in[17];
  const float* bv   = (const float*)d_in[18];
  const float* Wp   = (const float*)d_in[19];
  const float* bp   = (const float*)d_in[20];
  float* out = (float*)d_out;

  float* ws = (float*)d_ws;
  size_t off = 0;
  float* enc_out = ws + off; off += (size_t)Bb*Lmax*H2;     // 13,107,200
  float* c_buf   = ws + off; off += 2*Bb*Hh;                // 32,768
  float4* wip    = (float4*)(ws + off); off += 2*256*512*4; // 1,048,576
  float4* whp    = (float4*)(ws + off); off += 2*512*512*4; // 2,097,152
  float4* biasp  = (float4*)(ws + off); off += 2*512*4;     // 4,096
  float* cat_buf = ws + off; off += Bb*3*H2;
  float* prebuf  = ws + off; off += (size_t)Bb*Tt*H2;
  float* accumA  = ws + off; off += Bb*Lmax;
  float* accumB  = ws + off; off += Bb*Lmax;
  float* zi_buf  = ws + off; off += Bb*3*H2;
  float* zh_buf  = ws + off; off += (size_t)2*Bb*3*H2;      // 2 K-partials
  float* qp      = ws + off; off += (size_t)4*Bb*H2;        // 4 K-partials
  float* qdp     = ws + off; off += (size_t)4*Bb*H2;
  float* q       = ws + off; off += Bb*H2;
  float* qd      = ws + off; off += Bb*H2;
  float* h0      = ws + off; off += Bb*H2;
  float* esc     = ws + off; off += Bb*Lmax;
  float* enc_att = ws + off; off += Bb*Lmax;
  float* ed      = ws + off; off += Bb*Tt;
  float* logits  = ws + off; off += (size_t)Bb*Vv;
  int*   dec_in  = (int*)(ws + off); off += 32;
  unsigned short* Wbf = (unsigned short*)(ws + off);
  size_t need_bf16 = off*4 + (size_t)3*H2*Vv*2;             // bytes
  int use_bf16 = (ws_size >= need_bf16 + (64u<<10)) ? 1 : 0;

  // one-time packs (re-done every call: ws is re-poisoned)
  pack_enc_k<<<2048,256,0,stream>>>(Wi_f,Wh_f,b_f,Wi_b,Wh_b,b_b,wip,whp,biasp);
  if (use_bf16) pack_wv_k<<<96000,256,0,stream>>>(Wv, Wbf);

  for (int t = 0; t < Lmax; ++t)
    enc_step3_k<<<256,512,0,stream>>>(wip,whp,biasp,emb,x,c_buf,enc_out,t);

  init_dec_k<<<128,256,0,stream>>>(enc_out,cat_buf,h0,dec_in);

  for (int t = 0; t < Tt; ++t) {
    float* ar = (t & 1) ? accumB : accumA;   // read (old running sums); unused at t==0
    float* aw = (t & 1) ? accumA : accumB;   // write (new running sums)
    gru_mm_k  <<<768,256,0,stream>>>(emb,dec_in,cat_buf,dWi,dWh,db,zi_buf,zh_buf);
    qq_f_k    <<<512,256,0,stream>>>(zi_buf,zh_buf,h0,prebuf,Wea,Wda,cat_buf,qp,qdp,t);
    qsum_k    <<<32,256,0,stream>>>(qp,qdp,q,qd);
    att_sc_k  <<<3712,256,0,stream>>>(q,qd,enc_out,prebuf,esc,ed,t);
    ctx_norm_k<<<512,256,0,stream>>>(esc,ar,aw,enc_att,ed,enc_out,prebuf,cat_buf,t);
    if (use_bf16) wv_mm_bf_k<<<500,256,0,stream>>>(cat_buf,Wbf,bv,logits);
    else          wv_mm_k   <<<250,256,0,stream>>>(cat_buf,Wv,bv,logits);
    final_k   <<<32,256,0,stream>>>(logits,cat_buf,Wp,bp,ev,enc_att,tgt,out,dec_in,t);
  }
}